// Round 7
// baseline (2854.111 us; speedup 1.0000x reference)
//
#include <hip/hip_runtime.h>
#include <cmath>

#define TSEQ  256
#define ISZ   32
#define HSZ   512
#define OSZ   32
#define FUT   128

typedef float  f32x4 __attribute__((ext_vector_type(4)));
typedef short  s16x8 __attribute__((ext_vector_type(8)));
typedef unsigned int   uint32;
typedef unsigned int   u32x4 __attribute__((ext_vector_type(4)));
typedef unsigned short u16;

#define MFMA_BF16 __builtin_amdgcn_mfma_f32_16x16x32_bf16

__device__ __forceinline__ float sigm(float v) { return 1.0f / (1.0f + __expf(-v)); }

// ---- MALL-coherent (cross-XCD safe) access: sc0 sc1 bypass L1+L2 ----
template<int OFF>
__device__ __forceinline__ u32x4 ldH_cc(const uint32* p) {
    u32x4 d;
    asm volatile("global_load_dwordx4 %0, %1, off offset:%2 sc0 sc1"
                 : "=v"(d) : "v"(p), "n"(OFF) : "memory");
    return d;
}
template<int OFF>
__device__ __forceinline__ f32x4 ldX(const float* p) {   // normal cached
    f32x4 d;
    asm volatile("global_load_dwordx4 %0, %1, off offset:%2"
                 : "=v"(d) : "v"(p), "n"(OFF) : "memory");
    return d;
}
__device__ __forceinline__ void st32_cc(uint32* p, uint32 v) {
    asm volatile("global_store_dword %0, %1, off sc0 sc1" :: "v"(p), "v"(v) : "memory");
}
__device__ __forceinline__ uint32 ld32_cc(const uint32* p) {
    uint32 d;
    asm volatile("global_load_dword %0, %1, off sc0 sc1" : "=v"(d) : "v"(p) : "memory");
    return d;
}
#define WAITV(N) do { asm volatile("s_waitcnt vmcnt(" #N ")" ::: "memory"); \
                      __builtin_amdgcn_sched_barrier(0); } while (0)

// split 8 consecutive fp32 into bf16 hi / lo fragments (consecutive-k order)
__device__ __forceinline__ void split8(const float* p, s16x8& hi, s16x8& lo) {
    float v[8];
    *(f32x4*)&v[0] = *(const f32x4*)p;
    *(f32x4*)&v[4] = *(const f32x4*)(p + 4);
    uint32* ph = (uint32*)&hi; uint32* pl = (uint32*)&lo;
    #pragma unroll
    for (int q = 0; q < 4; ++q) {
        uint32 u0 = __float_as_uint(v[2*q]),   h0 = u0 & 0xFFFF0000u;
        uint32 u1 = __float_as_uint(v[2*q+1]), h1 = u1 & 0xFFFF0000u;
        float r0 = v[2*q]   - __uint_as_float(h0);
        float r1 = v[2*q+1] - __uint_as_float(h1);
        ph[q] = (h0 >> 16) | h1;
        pl[q] = (__float_as_uint(r0) >> 16) | (__float_as_uint(r1) & 0xFFFF0000u);
    }
}

// ---------------- prep: primed decoder weights + Wfc planes + biases ----------------
// Whh' = Whh + Wih @ Wfc ; b' = (b_ih+b_hh) + Wih @ b_fc  (exact fusion of
// pred -> x feedback in the decoder)
__global__ __launch_bounds__(512) void prep_weights(
    const float* __restrict__ Whh, const float* __restrict__ Wih,
    const float* __restrict__ Wfc, const float* __restrict__ bih,
    const float* __restrict__ bhh, const float* __restrict__ bfc,
    u16* WhpH, u16* WhpL, u16* WfcH, u16* WfcL,
    float* bsum, float* bsumP)
{
    const int r = (int)blockIdx.x;       // 0..2047 gate-row
    const int k = (int)threadIdx.x;      // 0..511
    float acc = Whh[(size_t)r * HSZ + k];
    #pragma unroll 8
    for (int i = 0; i < ISZ; ++i)
        acc += Wih[r * ISZ + i] * Wfc[i * HSZ + k];
    {
        uint32 u = __float_as_uint(acc), hu = u & 0xFFFF0000u;
        float rs = acc - __uint_as_float(hu);
        WhpH[(size_t)r * HSZ + k] = (u16)(u >> 16);
        WhpL[(size_t)r * HSZ + k] = (u16)(__float_as_uint(rs) >> 16);
    }
    if (r < OSZ) {
        float v = Wfc[r * HSZ + k];
        uint32 u = __float_as_uint(v), hu = u & 0xFFFF0000u;
        float rs = v - __uint_as_float(hu);
        WfcH[r * HSZ + k] = (u16)(u >> 16);
        WfcL[r * HSZ + k] = (u16)(__float_as_uint(rs) >> 16);
    }
    if (k == 0) {
        float b = bih[r] + bhh[r];
        float bp = b;
        #pragma unroll 8
        for (int i = 0; i < ISZ; ++i) bp += Wih[r * ISZ + i] * bfc[i];
        bsum[r] = b; bsumP[r] = bp;
    }
}

// ---------------- persistent MFMA LSTM, 2 independent domains per CU ----------------
// grid 512 = cg(16 col groups x 16 batch) x rg(32 unit groups x 16 units)
// block 256 = 4 waves: wave w = gate mr (i,f,g,o). 2 blocks/CU co-resident;
// the two cg-domains on a CU hide each other's MALL latency.
// Whh fragments in registers (split in-kernel from fp32). h exchanged as fused
// u32 (hi16|lo16) [col][k] via sc0/sc1 MALL ops (proven R5 path), double-buffered.
// Barrier: per-cg monotonic MALL atomic counter (32 blocks/domain).
__global__ __launch_bounds__(256, 2) void lstm_mfma4(
    const float* __restrict__ x,
    const float* __restrict__ Whh32, const float* __restrict__ Wih32,
    const float* __restrict__ b_fc,
    float* __restrict__ out,
    const u16* __restrict__ WhpHg, const u16* __restrict__ WhpLg,
    const u16* __restrict__ WfcHg, const u16* __restrict__ WfcLg,
    const float* __restrict__ bsum, const float* __restrict__ bsumP,
    uint32* hG0, uint32* hG1, uint32* mctr)
{
    __shared__ __align__(16) u16 bHi[2][16][256];   // [half][col][k swizzled]
    __shared__ __align__(16) u16 bLo[2][16][256];
    __shared__ float gatebuf[64][17];

    const int tid  = (int)threadIdx.x;
    const int cg   = (int)blockIdx.x & 15;
    const int rg   = (int)blockIdx.x >> 4;
    const int w    = tid >> 6, lane = tid & 63;
    const int mr   = w;                              // gate 0..3
    const int ks   = lane >> 4, lcol = lane & 15;
    const int ncol = lcol;                           // local batch col 0..15
    const bool dopred = (rg == 0) && (w < 2);        // pred rows o = mr*16+lcol
    const int prow = mr * 16 + lcol;

    const int grow = mr * HSZ + rg * 16 + lcol;      // gate-row [i,f,g,o]

    // ---- A fragments: split fp32 Whh/Wih in-kernel (encoder weights) ----
    s16x8 wH[16], wL[16];
    #pragma unroll
    for (int kt = 0; kt < 16; ++kt)
        split8(Whh32 + (size_t)grow * HSZ + kt * 32 + ks * 8, wH[kt], wL[kt]);
    s16x8 ihH, ihL;
    split8(Wih32 + (size_t)grow * ISZ + ks * 8, ihH, ihL);

    // ---- staging / epilogue mapping: col = tid>>4 (0..15), unit = tid&15 ----
    const int scol = tid >> 4, sli = tid & 15;
    const uint32* sb0 = hG0 + (size_t)(cg * 16 + scol) * HSZ + sli * 16;
    const uint32* sb1 = hG1 + (size_t)(cg * 16 + scol) * HSZ + sli * 16;
    const size_t hidx = (size_t)(cg * 16 + scol) * HSZ + rg * 16 + sli;
    uint32* hwA = hG1 + hidx;   // write target when tt even
    uint32* hwB = hG0 + hidx;   // write target when tt odd

    const float biv = bsum[           rg * 16 + sli];
    const float bfv = bsum[    HSZ  + rg * 16 + sli];
    const float bgv = bsum[2 * HSZ  + rg * 16 + sli];
    const float bov = bsum[3 * HSZ  + rg * 16 + sli];
    const float biP = bsumP[           rg * 16 + sli];
    const float bfP = bsumP[    HSZ  + rg * 16 + sli];
    const float bgP = bsumP[2 * HSZ  + rg * 16 + sli];
    const float boP = bsumP[3 * HSZ  + rg * 16 + sli];
    float pbq[4] = {0.f, 0.f, 0.f, 0.f};
    if (w < 2) {
        #pragma unroll
        for (int q = 0; q < 4; ++q) pbq[q] = b_fc[mr * 16 + ks * 4 + q];
    }

    const float* xbase = x + (size_t)(cg * 16 + lcol) * (TSEQ * ISZ) + ks * 8;
    float* outp = out + (size_t)(cg * 16 + lcol) * (FUT * OSZ);
    uint32* ctrp = mctr + cg * 16;   // 64B-spaced per-cg counters

    float cst = 0.f;
    __syncthreads();

#define ISSUE8() do { \
    sreg[0] = ldH_cc<0>(sb);    sreg[1] = ldH_cc<16>(sb);   \
    sreg[2] = ldH_cc<32>(sb);   sreg[3] = ldH_cc<48>(sb);   \
    sreg[4] = ldH_cc<1024>(sb); sreg[5] = ldH_cc<1040>(sb); \
    sreg[6] = ldH_cc<1056>(sb); sreg[7] = ldH_cc<1072>(sb); } while (0)

#define STAGE_WR(H)                                                            \
    { _Pragma("unroll")                                                        \
      for (int j = 0; j < 4; ++j) {                                            \
          u32x4 v = sreg[(H) * 4 + j];                                         \
          uint32 h0 = (v[0] >> 16) | (v[1] & 0xFFFF0000u);                     \
          uint32 h1 = (v[2] >> 16) | (v[3] & 0xFFFF0000u);                     \
          uint32 l0 = (v[0] & 0xFFFFu) | (v[1] << 16);                         \
          uint32 l1 = (v[2] & 0xFFFFu) | (v[3] << 16);                         \
          int go = (((sli * 2 + (j >> 1)) ^ scol) << 3) + ((j & 1) * 4);       \
          *(uint2*)&bHi[H][scol][go] = make_uint2(h0, h1);                     \
          *(uint2*)&bLo[H][scol][go] = make_uint2(l0, l1);                     \
      } }

#define CONS_KT(H, KTL)                                                        \
    { const int g = ((((KTL) * 4) + ks) ^ lcol) << 3;                          \
      s16x8 bh = *(const s16x8*)&bHi[H][ncol][g];                              \
      s16x8 bl = *(const s16x8*)&bLo[H][ncol][g];                              \
      gA = MFMA_BF16(wH[(H) * 8 + (KTL)], bh, gA, 0, 0, 0);                    \
      gB = MFMA_BF16(wH[(H) * 8 + (KTL)], bl, gB, 0, 0, 0);                    \
      gC = MFMA_BF16(wL[(H) * 8 + (KTL)], bh, gC, 0, 0, 0);                    \
      if (dec && dopred) {                                                     \
          s16x8 fh = *(const s16x8*)(WfcHg + (size_t)prow * HSZ                \
                                     + ((H) * 8 + (KTL)) * 32 + ks * 8);       \
          s16x8 fl = *(const s16x8*)(WfcLg + (size_t)prow * HSZ                \
                                     + ((H) * 8 + (KTL)) * 32 + ks * 8);       \
          pA = MFMA_BF16(fh, bh, pA, 0, 0, 0);                                 \
          pB = MFMA_BF16(fh, bl, pB, 0, 0, 0);                                 \
          pC = MFMA_BF16(fl, bh, pC, 0, 0, 0);                                 \
      } }
#define CONS_HALF(H) \
    CONS_KT(H,0) CONS_KT(H,1) CONS_KT(H,2) CONS_KT(H,3) \
    CONS_KT(H,4) CONS_KT(H,5) CONS_KT(H,6) CONS_KT(H,7)

    #pragma unroll 1
    for (int tt = 0; tt < TSEQ + FUT; ++tt) {
        const bool dec = (tt >= TSEQ);
        const uint32* sb = (tt & 1) ? sb1 : sb0;
        uint32* hwp = (tt & 1) ? hwB : hwA;

        if (tt == TSEQ) {   // one-time switch to primed (fused) decoder weights
            #pragma unroll
            for (int kt = 0; kt < 16; ++kt) {
                wH[kt] = *(const s16x8*)(WhpHg + (size_t)grow * HSZ + kt * 32 + ks * 8);
                wL[kt] = *(const s16x8*)(WhpLg + (size_t)grow * HSZ + kt * 32 + ks * 8);
            }
        }

        f32x4 gA = {0,0,0,0}, gB = {0,0,0,0}, gC = {0,0,0,0};
        f32x4 pA = {0,0,0,0}, pB = {0,0,0,0}, pC = {0,0,0,0};
        f32x4 xv0 = {0,0,0,0}, xv1 = {0,0,0,0};

        if (!dec) {   // x loads first (oldest in vmcnt order)
            const float* xp = xbase + (size_t)tt * ISZ;
            xv0 = ldX<0>(xp); xv1 = ldX<16>(xp);
        }
        u32x4 sreg[8];
        ISSUE8();

        if (!dec) {
            WAITV(8);   // x done; h stage still in flight
            s16x8 xh, xl;
            float xv[8];
            *(f32x4*)&xv[0] = xv0; *(f32x4*)&xv[4] = xv1;
            split8(xv, xh, xl);
            gA = MFMA_BF16(ihH, xh, gA, 0, 0, 0);
            gB = MFMA_BF16(ihH, xl, gB, 0, 0, 0);
            gC = MFMA_BF16(ihL, xh, gC, 0, 0, 0);
        }

        WAITV(4);          // half0 arrived
        STAGE_WR(0);
        __syncthreads();
        CONS_HALF(0);      // half1 in flight under these MFMAs
        WAITV(0);
        STAGE_WR(1);
        __syncthreads();
        CONS_HALF(1);

        if (dec && dopred) {   // rg0 blocks compute pred for the output
            f32x4 pr = pA + pB + pC;
            const int step = tt - TSEQ;
            #pragma unroll
            for (int q = 0; q < 4; ++q)
                outp[(size_t)step * OSZ + mr * 16 + ks * 4 + q] = pr[q] + pbq[q];
        }

        // ---- gates -> LDS bounce ----
        f32x4 gt = gA + gB + gC;
        #pragma unroll
        for (int q = 0; q < 4; ++q)
            gatebuf[mr * 16 + ks * 4 + q][ncol] = gt[q];
        __syncthreads();

        // ---- cell update (thread = col scol, unit sli) + publish fused h ----
        {
            float gi = gatebuf[     sli][scol] + (dec ? biP : biv);
            float gf = gatebuf[16 + sli][scol] + (dec ? bfP : bfv);
            float gg = gatebuf[32 + sli][scol] + (dec ? bgP : bgv);
            float go = gatebuf[48 + sli][scol] + (dec ? boP : bov);
            cst = sigm(gf) * cst + sigm(gi) * tanhf(gg);
            float hv = sigm(go) * tanhf(cst);
            uint32 u = __float_as_uint(hv), hu = u & 0xFFFF0000u;
            float rs = hv - __uint_as_float(hu);
            st32_cc(hwp, hu | (__float_as_uint(rs) >> 16));
        }

        // ---- barrier: drain -> MALL atomic count -> poll (proven R5 path) ----
        WAITV(0);
        __syncthreads();
        if (tid == 0) {
            __hip_atomic_fetch_add(ctrp, 1u, __ATOMIC_RELAXED, __HIP_MEMORY_SCOPE_AGENT);
            const uint32 tgt = 32u * (uint32)(tt + 1);
            int guard = 0;
            for (;;) {
                uint32 v = ld32_cc(ctrp);
                WAITV(0);
                if (v >= tgt || guard > (1 << 14)) break;
                __builtin_amdgcn_s_sleep(1); ++guard;
            }
        }
        __syncthreads();
    }
#undef ISSUE8
#undef STAGE_WR
#undef CONS_KT
#undef CONS_HALF
}

extern "C" void kernel_launch(void* const* d_in, const int* in_sizes, int n_in,
                              void* d_out, int out_size, void* d_ws, size_t ws_size,
                              hipStream_t stream)
{
    (void)in_sizes; (void)n_in; (void)out_size; (void)ws_size;
    const float* x    = (const float*)d_in[0];
    const float* W_ih = (const float*)d_in[1];
    const float* W_hh = (const float*)d_in[2];
    const float* b_ih = (const float*)d_in[3];
    const float* b_hh = (const float*)d_in[4];
    const float* W_fc = (const float*)d_in[5];
    const float* b_fc = (const float*)d_in[6];
    float* out = (float*)d_out;

    char* ws = (char*)d_ws;
    uint32* mctr = (uint32*)(ws);                  // 1 KB: 16 counters, 64B apart
    uint32* hG0  = (uint32*)(ws + 4096);           // 512 KB fused h buf 0
    uint32* hG1  = (uint32*)(ws + 4096 + 524288);  // 512 KB fused h buf 1
    u16* WhpH  = (u16*)(ws + 1052672);             // 2 MB primed Whh' hi
    u16* WhpL  = (u16*)(ws + 3149824);             // 2 MB primed Whh' lo
    u16* WfcH  = (u16*)(ws + 5246976);             // 32 KB
    u16* WfcL  = (u16*)(ws + 5279744);             // 32 KB
    float* bsum  = (float*)(ws + 5312512);         // 8 KB
    float* bsumP = (float*)(ws + 5320704);         // 8 KB

    // zero counters + hG0 (initial hidden state)
    hipMemsetAsync(ws, 0, 4096 + 524288, stream);

    prep_weights<<<2048, 512, 0, stream>>>(W_hh, W_ih, W_fc, b_ih, b_hh, b_fc,
                                           WhpH, WhpL, WfcH, WfcL, bsum, bsumP);

    lstm_mfma4<<<512, 256, 0, stream>>>(x, W_hh, W_ih, b_fc, out,
                                        WhpH, WhpL, WfcH, WfcL, bsum, bsumP,
                                        hG0, hG1, mctr);
}

// Round 8
// 1859.799 us; speedup vs baseline: 1.5346x; 1.5346x over previous
//
#include <hip/hip_runtime.h>
#include <cmath>

#define TSEQ  256
#define ISZ   32
#define HSZ   512
#define OSZ   32
#define FUT   128

typedef float  f32x4 __attribute__((ext_vector_type(4)));
typedef short  s16x8 __attribute__((ext_vector_type(8)));
typedef unsigned int   uint32;
typedef unsigned int   u32x4 __attribute__((ext_vector_type(4)));
typedef unsigned short u16;

#define MFMA_BF16 __builtin_amdgcn_mfma_f32_16x16x32_bf16

__device__ __forceinline__ float sigm(float v) { return 1.0f / (1.0f + __expf(-v)); }

// ---- MALL-coherent (cross-XCD safe) access: sc0 sc1 bypass L1+L2 ----
template<int OFF>
__device__ __forceinline__ u32x4 ldH_cc(const uint32* p) {
    u32x4 d;
    asm volatile("global_load_dwordx4 %0, %1, off offset:%2 sc0 sc1"
                 : "=v"(d) : "v"(p), "n"(OFF) : "memory");
    return d;
}
template<int OFF>
__device__ __forceinline__ f32x4 ldX(const float* p) {   // normal cached
    f32x4 d;
    asm volatile("global_load_dwordx4 %0, %1, off offset:%2"
                 : "=v"(d) : "v"(p), "n"(OFF) : "memory");
    return d;
}
__device__ __forceinline__ void st32_cc(uint32* p, uint32 v) {
    asm volatile("global_store_dword %0, %1, off sc0 sc1" :: "v"(p), "v"(v) : "memory");
}
__device__ __forceinline__ uint32 ld32_cc(const uint32* p) {
    uint32 d;
    asm volatile("global_load_dword %0, %1, off sc0 sc1" : "=v"(d) : "v"(p) : "memory");
    return d;
}
#define WAITV(N) do { asm volatile("s_waitcnt vmcnt(" #N ")" ::: "memory"); \
                      __builtin_amdgcn_sched_barrier(0); } while (0)

// split 8 consecutive fp32 into bf16 hi / lo fragments (consecutive-k order)
__device__ __forceinline__ void split8(const float* p, s16x8& hi, s16x8& lo) {
    float v[8];
    *(f32x4*)&v[0] = *(const f32x4*)p;
    *(f32x4*)&v[4] = *(const f32x4*)(p + 4);
    uint32* ph = (uint32*)&hi; uint32* pl = (uint32*)&lo;
    #pragma unroll
    for (int q = 0; q < 4; ++q) {
        uint32 u0 = __float_as_uint(v[2*q]),   h0 = u0 & 0xFFFF0000u;
        uint32 u1 = __float_as_uint(v[2*q+1]), h1 = u1 & 0xFFFF0000u;
        float r0 = v[2*q]   - __uint_as_float(h0);
        float r1 = v[2*q+1] - __uint_as_float(h1);
        ph[q] = (h0 >> 16) | h1;
        pl[q] = (__float_as_uint(r0) >> 16) | (__float_as_uint(r1) & 0xFFFF0000u);
    }
}

// ---------------- prep: primed decoder weights + Wfc planes + biases ----------------
// Whh' = Whh + Wih @ Wfc ; b' = (b_ih+b_hh) + Wih @ b_fc  (exact decoder fusion)
__global__ __launch_bounds__(512) void prep_weights(
    const float* __restrict__ Whh, const float* __restrict__ Wih,
    const float* __restrict__ Wfc, const float* __restrict__ bih,
    const float* __restrict__ bhh, const float* __restrict__ bfc,
    u16* WhpH, u16* WhpL, u16* WfcH, u16* WfcL,
    float* bsum, float* bsumP)
{
    const int r = (int)blockIdx.x;       // 0..2047 gate-row
    const int k = (int)threadIdx.x;      // 0..511
    float acc = Whh[(size_t)r * HSZ + k];
    #pragma unroll 8
    for (int i = 0; i < ISZ; ++i)
        acc += Wih[r * ISZ + i] * Wfc[i * HSZ + k];
    {
        uint32 u = __float_as_uint(acc), hu = u & 0xFFFF0000u;
        float rs = acc - __uint_as_float(hu);
        WhpH[(size_t)r * HSZ + k] = (u16)(u >> 16);
        WhpL[(size_t)r * HSZ + k] = (u16)(__float_as_uint(rs) >> 16);
    }
    if (r < OSZ) {
        float v = Wfc[r * HSZ + k];
        uint32 u = __float_as_uint(v), hu = u & 0xFFFF0000u;
        float rs = v - __uint_as_float(hu);
        WfcH[r * HSZ + k] = (u16)(u >> 16);
        WfcL[r * HSZ + k] = (u16)(__float_as_uint(rs) >> 16);
    }
    if (k == 0) {
        float b = bih[r] + bhh[r];
        float bp = b;
        #pragma unroll 8
        for (int i = 0; i < ISZ; ++i) bp += Wih[r * ISZ + i] * bfc[i];
        bsum[r] = b; bsumP[r] = bp;
    }
}

// ---------------- persistent MFMA LSTM, U=32 units per block ----------------
// grid 256 = cg(16 domains x 16 batch cols) x rg(16 unit groups x 32 units)
// block 512 = 8 waves: wave w -> gate g = w>>1, unit-half = w&1.
// Rows/block = 128 (32 units x 4 gates); Whh frags in 128 VGPR/thread.
// h exchanged as fused u32 (hi16|lo16) [col][k] via sc0/sc1, double-buffered.
// Barrier: per-producer flag stores + lane-parallel vector poll (16 slots).
__global__ __launch_bounds__(512, 1) void lstm_mfma5(
    const float* __restrict__ x,
    const float* __restrict__ Whh32, const float* __restrict__ Wih32,
    const float* __restrict__ b_fc,
    float* __restrict__ out,
    const u16* __restrict__ WhpHg, const u16* __restrict__ WhpLg,
    const u16* __restrict__ WfcHg, const u16* __restrict__ WfcLg,
    const float* __restrict__ bsum, const float* __restrict__ bsumP,
    uint32* hG0, uint32* hG1, uint32* flg)
{
    __shared__ __align__(16) u16 bHi[2][16][256];   // [half][col][k swizzled]
    __shared__ __align__(16) u16 bLo[2][16][256];
    __shared__ float gatebuf[128][17];

    const int tid  = (int)threadIdx.x;
    const int cg   = (int)blockIdx.x & 15;
    const int rg   = (int)blockIdx.x >> 4;
    const int w    = tid >> 6, lane = tid & 63;
    const int ks   = lane >> 4, lcol = lane & 15;
    const bool dopred = (rg == 0) && (w < 2);       // pred rows o = w*16+..
    const int prow = w * 16 + lcol;

    // gate-row: gate g = w>>1, unit = rg*32 + (w&1)*16 + lcol
    const int grow = (w >> 1) * HSZ + rg * 32 + (w & 1) * 16 + lcol;

    // ---- A fragments: split fp32 Whh/Wih in-kernel (encoder weights) ----
    s16x8 wH[16], wL[16];
    #pragma unroll
    for (int kt = 0; kt < 16; ++kt)
        split8(Whh32 + (size_t)grow * HSZ + kt * 32 + ks * 8, wH[kt], wL[kt]);
    s16x8 ihH, ihL;
    split8(Wih32 + (size_t)grow * ISZ + ks * 8, ihH, ihL);

    // ---- staging / epilogue mapping: col = tid>>5 (0..15), granule/unit = tid&31 ----
    const int scol = tid >> 5, skb = tid & 31;
    const uint32* sb0 = hG0 + (size_t)(cg * 16 + scol) * HSZ + skb * 8;
    const uint32* sb1 = hG1 + (size_t)(cg * 16 + scol) * HSZ + skb * 8;
    const size_t hidx = (size_t)(cg * 16 + scol) * HSZ + rg * 32 + skb;
    uint32* hwA = hG1 + hidx;   // write target when tt even
    uint32* hwB = hG0 + hidx;   // write target when tt odd

    const float biv = bsum [           rg * 32 + skb];
    const float bfv = bsum [    HSZ  + rg * 32 + skb];
    const float bgv = bsum [2 * HSZ  + rg * 32 + skb];
    const float bov = bsum [3 * HSZ  + rg * 32 + skb];
    const float biP = bsumP[           rg * 32 + skb];
    const float bfP = bsumP[    HSZ  + rg * 32 + skb];
    const float bgP = bsumP[2 * HSZ  + rg * 32 + skb];
    const float boP = bsumP[3 * HSZ  + rg * 32 + skb];
    float pbq[4] = {0.f, 0.f, 0.f, 0.f};
    if (w < 2) {
        #pragma unroll
        for (int q = 0; q < 4; ++q) pbq[q] = b_fc[w * 16 + ks * 4 + q];
    }

    const float* xbase = x + (size_t)(cg * 16 + lcol) * (TSEQ * ISZ) + ks * 8;
    float* outp = out + (size_t)(cg * 16 + lcol) * (FUT * OSZ);
    uint32* myflag = flg + ((cg * 16 + rg) << 4);   // 64B-padded slots

    float cst = 0.f;
    __syncthreads();

#define STAGE_WR(H)                                                            \
    { u32x4 v0 = sreg[(H) * 2], v1 = sreg[(H) * 2 + 1];                        \
      u32x4 hw_, lw_;                                                          \
      hw_[0] = (v0[0] >> 16) | (v0[1] & 0xFFFF0000u);                          \
      hw_[1] = (v0[2] >> 16) | (v0[3] & 0xFFFF0000u);                          \
      hw_[2] = (v1[0] >> 16) | (v1[1] & 0xFFFF0000u);                          \
      hw_[3] = (v1[2] >> 16) | (v1[3] & 0xFFFF0000u);                          \
      lw_[0] = (v0[0] & 0xFFFFu) | (v0[1] << 16);                              \
      lw_[1] = (v0[2] & 0xFFFFu) | (v0[3] << 16);                              \
      lw_[2] = (v1[0] & 0xFFFFu) | (v1[1] << 16);                              \
      lw_[3] = (v1[2] & 0xFFFFu) | (v1[3] << 16);                              \
      const int go = (skb ^ scol) << 3;                                        \
      *(u32x4*)&bHi[H][scol][go] = hw_;                                        \
      *(u32x4*)&bLo[H][scol][go] = lw_; }

#define CONS_KT(H, KTL)                                                        \
    { const int g = ((((KTL) * 4) + ks) ^ lcol) << 3;                          \
      s16x8 bh = *(const s16x8*)&bHi[H][lcol][g];                              \
      s16x8 bl = *(const s16x8*)&bLo[H][lcol][g];                              \
      gA = MFMA_BF16(wH[(H) * 8 + (KTL)], bh, gA, 0, 0, 0);                    \
      gB = MFMA_BF16(wH[(H) * 8 + (KTL)], bl, gB, 0, 0, 0);                    \
      gC = MFMA_BF16(wL[(H) * 8 + (KTL)], bh, gC, 0, 0, 0);                    \
      if (dec && dopred) {                                                     \
          s16x8 fh = *(const s16x8*)(WfcHg + (size_t)prow * HSZ                \
                                     + ((H) * 8 + (KTL)) * 32 + ks * 8);       \
          s16x8 fl = *(const s16x8*)(WfcLg + (size_t)prow * HSZ                \
                                     + ((H) * 8 + (KTL)) * 32 + ks * 8);       \
          pA = MFMA_BF16(fh, bh, pA, 0, 0, 0);                                 \
          pB = MFMA_BF16(fh, bl, pB, 0, 0, 0);                                 \
          pC = MFMA_BF16(fl, bh, pC, 0, 0, 0);                                 \
      } }
#define CONS_HALF(H) \
    CONS_KT(H,0) CONS_KT(H,1) CONS_KT(H,2) CONS_KT(H,3) \
    CONS_KT(H,4) CONS_KT(H,5) CONS_KT(H,6) CONS_KT(H,7)

    #pragma unroll 1
    for (int tt = 0; tt < TSEQ + FUT; ++tt) {
        const bool dec = (tt >= TSEQ);
        const uint32* sb = (tt & 1) ? sb1 : sb0;
        uint32* hwp = (tt & 1) ? hwB : hwA;

        if (tt == TSEQ) {   // one-time switch to primed (fused) decoder weights
            #pragma unroll
            for (int kt = 0; kt < 16; ++kt) {
                wH[kt] = *(const s16x8*)(WhpHg + (size_t)grow * HSZ + kt * 32 + ks * 8);
                wL[kt] = *(const s16x8*)(WhpLg + (size_t)grow * HSZ + kt * 32 + ks * 8);
            }
        }

        f32x4 gA = {0,0,0,0}, gB = {0,0,0,0}, gC = {0,0,0,0};
        f32x4 pA = {0,0,0,0}, pB = {0,0,0,0}, pC = {0,0,0,0};
        f32x4 xv0 = {0,0,0,0}, xv1 = {0,0,0,0};
        u32x4 sreg[4];

        if (!dec) {   // x loads first (oldest in vmcnt order)
            const float* xp = xbase + (size_t)tt * ISZ;
            xv0 = ldX<0>(xp); xv1 = ldX<16>(xp);
        }
        // h loads: half0 (k 0..255) then half1 (k 256..511); 32B/thread each
        sreg[0] = ldH_cc<0>(sb);    sreg[1] = ldH_cc<16>(sb);
        sreg[2] = ldH_cc<1024>(sb); sreg[3] = ldH_cc<1040>(sb);

        if (!dec) {
            WAITV(4);   // x done; h still in flight
            s16x8 xh, xl;
            float xv[8];
            *(f32x4*)&xv[0] = xv0; *(f32x4*)&xv[4] = xv1;
            split8(xv, xh, xl);
            gA = MFMA_BF16(ihH, xh, gA, 0, 0, 0);
            gB = MFMA_BF16(ihH, xl, gB, 0, 0, 0);
            gC = MFMA_BF16(ihL, xh, gC, 0, 0, 0);
        }

        WAITV(2);          // half0 arrived
        STAGE_WR(0);
        __syncthreads();
        CONS_HALF(0);      // half1 in flight under these MFMAs
        WAITV(0);
        STAGE_WR(1);
        __syncthreads();
        CONS_HALF(1);

        if (dec && dopred) {   // rg0 blocks compute pred for the output
            f32x4 pr = pA + pB + pC;
            const int step = tt - TSEQ;
            #pragma unroll
            for (int q = 0; q < 4; ++q)
                outp[(size_t)step * OSZ + w * 16 + ks * 4 + q] = pr[q] + pbq[q];
        }

        // ---- gates -> LDS bounce ----
        f32x4 gt = gA + gB + gC;
        #pragma unroll
        for (int q = 0; q < 4; ++q)
            gatebuf[w * 16 + ks * 4 + q][lcol] = gt[q];
        __syncthreads();

        // ---- cell update (thread = col scol, unit skb) + publish fused h ----
        {
            float gi = gatebuf[      skb][scol] + (dec ? biP : biv);
            float gf = gatebuf[ 32 + skb][scol] + (dec ? bfP : bfv);
            float gg = gatebuf[ 64 + skb][scol] + (dec ? bgP : bgv);
            float go = gatebuf[ 96 + skb][scol] + (dec ? boP : bov);
            cst = sigm(gf) * cst + sigm(gi) * tanhf(gg);
            float hv = sigm(go) * tanhf(cst);
            uint32 u = __float_as_uint(hv), hu = u & 0xFFFF0000u;
            float rs = hv - __uint_as_float(hu);
            st32_cc(hwp, hu | (__float_as_uint(rs) >> 16));
        }

        // ---- barrier: drain -> flag store -> lane-parallel vector poll ----
        WAITV(0);
        __syncthreads();
        const uint32 token = (uint32)tt + 1u;
        if (tid == 0) st32_cc(myflag, token);
        if (tid < 16) {
            const uint32* fp = flg + ((cg * 16 + tid) << 4);
            int guard = 0;
            for (;;) {
                uint32 v = ld32_cc(fp);
                WAITV(0);
                if (__all(v >= token) || guard > (1 << 13)) break;
                __builtin_amdgcn_s_sleep(1); ++guard;
            }
        }
        __syncthreads();
    }
#undef STAGE_WR
#undef CONS_KT
#undef CONS_HALF
}

extern "C" void kernel_launch(void* const* d_in, const int* in_sizes, int n_in,
                              void* d_out, int out_size, void* d_ws, size_t ws_size,
                              hipStream_t stream)
{
    (void)in_sizes; (void)n_in; (void)out_size; (void)ws_size;
    const float* x    = (const float*)d_in[0];
    const float* W_ih = (const float*)d_in[1];
    const float* W_hh = (const float*)d_in[2];
    const float* b_ih = (const float*)d_in[3];
    const float* b_hh = (const float*)d_in[4];
    const float* W_fc = (const float*)d_in[5];
    const float* b_fc = (const float*)d_in[6];
    float* out = (float*)d_out;

    char* ws = (char*)d_ws;
    uint32* flg  = (uint32*)(ws);                   // 16 KB: 256 slots, 64B apart
    uint32* hG0  = (uint32*)(ws + 16384);           // 512 KB fused h buf 0
    uint32* hG1  = (uint32*)(ws + 540672);          // 512 KB fused h buf 1
    u16* WhpH  = (u16*)(ws + 1064960);              // 2 MB primed Whh' hi
    u16* WhpL  = (u16*)(ws + 3162112);              // 2 MB primed Whh' lo
    u16* WfcH  = (u16*)(ws + 5259264);              // 32 KB
    u16* WfcL  = (u16*)(ws + 5292032);              // 32 KB
    float* bsum  = (float*)(ws + 5324800);          // 8 KB
    float* bsumP = (float*)(ws + 5332992);          // 8 KB

    // zero flags + hG0 (initial hidden state)
    hipMemsetAsync(ws, 0, 16384 + 524288, stream);

    prep_weights<<<2048, 512, 0, stream>>>(W_hh, W_ih, W_fc, b_ih, b_hh, b_fc,
                                           WhpH, WhpL, WfcH, WfcL, bsum, bsumP);

    lstm_mfma5<<<256, 512, 0, stream>>>(x, W_hh, W_ih, b_fc, out,
                                        WhpH, WhpL, WfcH, WfcL, bsum, bsumP,
                                        hG0, hG1, flg);
}

// Round 9
// 1665.159 us; speedup vs baseline: 1.7140x; 1.1169x over previous
//
#include <hip/hip_runtime.h>
#include <cmath>

#define TSEQ  256
#define ISZ   32
#define HSZ   512
#define OSZ   32
#define FUT   128

typedef float  f32x4 __attribute__((ext_vector_type(4)));
typedef short  s16x8 __attribute__((ext_vector_type(8)));
typedef unsigned int   uint32;
typedef unsigned int   u32x4 __attribute__((ext_vector_type(4)));
typedef unsigned short u16;

#define MFMA_BF16 __builtin_amdgcn_mfma_f32_16x16x32_bf16

__device__ __forceinline__ float sigm(float v) { return 1.0f / (1.0f + __expf(-v)); }

// ---- MALL-coherent (cross-XCD safe) access: sc0 sc1 bypass L1+L2 ----
template<int OFF>
__device__ __forceinline__ u32x4 ldH_cc(const uint32* p) {
    u32x4 d;
    asm volatile("global_load_dwordx4 %0, %1, off offset:%2 sc0 sc1"
                 : "=v"(d) : "v"(p), "n"(OFF) : "memory");
    return d;
}
template<int OFF>
__device__ __forceinline__ f32x4 ldX(const float* p) {   // normal cached
    f32x4 d;
    asm volatile("global_load_dwordx4 %0, %1, off offset:%2"
                 : "=v"(d) : "v"(p), "n"(OFF) : "memory");
    return d;
}
__device__ __forceinline__ void st32_cc(uint32* p, uint32 v) {
    asm volatile("global_store_dword %0, %1, off sc0 sc1" :: "v"(p), "v"(v) : "memory");
}
#define WAITV(N) do { asm volatile("s_waitcnt vmcnt(" #N ")" ::: "memory"); \
                      __builtin_amdgcn_sched_barrier(0); } while (0)

// split 8 consecutive fp32 into bf16 hi / lo fragments (consecutive-k order)
__device__ __forceinline__ void split8(const float* p, s16x8& hi, s16x8& lo) {
    float v[8];
    *(f32x4*)&v[0] = *(const f32x4*)p;
    *(f32x4*)&v[4] = *(const f32x4*)(p + 4);
    uint32* ph = (uint32*)&hi; uint32* pl = (uint32*)&lo;
    #pragma unroll
    for (int q = 0; q < 4; ++q) {
        uint32 u0 = __float_as_uint(v[2*q]),   h0 = u0 & 0xFFFF0000u;
        uint32 u1 = __float_as_uint(v[2*q+1]), h1 = u1 & 0xFFFF0000u;
        float r0 = v[2*q]   - __uint_as_float(h0);
        float r1 = v[2*q+1] - __uint_as_float(h1);
        ph[q] = (h0 >> 16) | h1;
        pl[q] = (__float_as_uint(r0) >> 16) | (__float_as_uint(r1) & 0xFFFF0000u);
    }
}

// ---------------- prep: primed decoder weights + Wfc planes + biases ----------------
// Whh' = Whh + Wih @ Wfc ; b' = (b_ih+b_hh) + Wih @ b_fc  (exact decoder fusion)
__global__ __launch_bounds__(512) void prep_weights(
    const float* __restrict__ Whh, const float* __restrict__ Wih,
    const float* __restrict__ Wfc, const float* __restrict__ bih,
    const float* __restrict__ bhh, const float* __restrict__ bfc,
    u16* WhpH, u16* WhpL, u16* WfcH, u16* WfcL,
    float* bsum, float* bsumP)
{
    const int r = (int)blockIdx.x;       // 0..2047 gate-row
    const int k = (int)threadIdx.x;      // 0..511
    float acc = Whh[(size_t)r * HSZ + k];
    #pragma unroll 8
    for (int i = 0; i < ISZ; ++i)
        acc += Wih[r * ISZ + i] * Wfc[i * HSZ + k];
    {
        uint32 u = __float_as_uint(acc), hu = u & 0xFFFF0000u;
        float rs = acc - __uint_as_float(hu);
        WhpH[(size_t)r * HSZ + k] = (u16)(u >> 16);
        WhpL[(size_t)r * HSZ + k] = (u16)(__float_as_uint(rs) >> 16);
    }
    if (r < OSZ) {
        float v = Wfc[r * HSZ + k];
        uint32 u = __float_as_uint(v), hu = u & 0xFFFF0000u;
        float rs = v - __uint_as_float(hu);
        WfcH[r * HSZ + k] = (u16)(u >> 16);
        WfcL[r * HSZ + k] = (u16)(__float_as_uint(rs) >> 16);
    }
    if (k == 0) {
        float b = bih[r] + bhh[r];
        float bp = b;
        #pragma unroll 8
        for (int i = 0; i < ISZ; ++i) bp += Wih[r * ISZ + i] * bfc[i];
        bsum[r] = b; bsumP[r] = bp;
    }
}

// ---------------- persistent MFMA LSTM, barrier-free self-certifying exchange ----------------
// grid 256 = cg(16 domains x 16 batch cols) x rg(16 unit groups x 32 units)
// block 512 = 8 waves: wave w -> gate g = w>>1, unit-half = w&1.
// h exchanged as fused u32 (bf16hi<<16 | bf16lo) with its LSB stolen for an
// EPOCH PARITY BIT: write of step t -> buf[t&3], bit = ~(t>>2)&1. A reader of
// step s loads buf[(s-1)&3] speculatively and retries until every word's LSB
// matches ~((s-1)>>2)&1. No flags, no vmcnt publish drain, no barrier.
// Drift between blocks is bounded to 1 step by the data dependency itself, so
// with 4 buffers no live line is ever clobbered (proof in round notes).
__global__ __launch_bounds__(512, 1) void lstm_mfma6(
    const float* __restrict__ x,
    const float* __restrict__ Whh32, const float* __restrict__ Wih32,
    const float* __restrict__ b_fc,
    float* __restrict__ out,
    const u16* __restrict__ WhpHg, const u16* __restrict__ WhpLg,
    const u16* __restrict__ WfcHg, const u16* __restrict__ WfcLg,
    const float* __restrict__ bsum, const float* __restrict__ bsumP,
    uint32* hBase)
{
    __shared__ __align__(16) u16 bHi[2][16][256];   // [half][col][k swizzled]
    __shared__ __align__(16) u16 bLo[2][16][256];
    __shared__ float gatebuf[128][17];
    __shared__ int vfail;

    const int tid  = (int)threadIdx.x;
    const int cg   = (int)blockIdx.x & 15;
    const int rg   = (int)blockIdx.x >> 4;
    const int w    = tid >> 6, lane = tid & 63;
    const int ks   = lane >> 4, lcol = lane & 15;
    const bool dopred = (rg == 0) && (w < 2);       // pred rows o = w*16+..
    const int prow = w * 16 + lcol;

    // gate-row: gate g = w>>1, unit = rg*32 + (w&1)*16 + lcol
    const int grow = (w >> 1) * HSZ + rg * 32 + (w & 1) * 16 + lcol;

    // ---- A fragments: split fp32 Whh/Wih in-kernel (encoder weights) ----
    s16x8 wH[16], wL[16];
    #pragma unroll
    for (int kt = 0; kt < 16; ++kt)
        split8(Whh32 + (size_t)grow * HSZ + kt * 32 + ks * 8, wH[kt], wL[kt]);
    s16x8 ihH, ihL;
    split8(Wih32 + (size_t)grow * ISZ + ks * 8, ihH, ihL);

    // ---- staging / epilogue mapping: col = tid>>5 (0..15), unit = tid&31 ----
    const int scol = tid >> 5, skb = tid & 31;
    const size_t sboff = (size_t)(cg * 16 + scol) * HSZ + skb * 8;   // read base
    const size_t hoff  = (size_t)(cg * 16 + scol) * HSZ + rg * 32 + skb;  // write

    const float biv = bsum [           rg * 32 + skb];
    const float bfv = bsum [    HSZ  + rg * 32 + skb];
    const float bgv = bsum [2 * HSZ  + rg * 32 + skb];
    const float bov = bsum [3 * HSZ  + rg * 32 + skb];
    const float biP = bsumP[           rg * 32 + skb];
    const float bfP = bsumP[    HSZ  + rg * 32 + skb];
    const float bgP = bsumP[2 * HSZ  + rg * 32 + skb];
    const float boP = bsumP[3 * HSZ  + rg * 32 + skb];
    float pbq[4] = {0.f, 0.f, 0.f, 0.f};
    if (w < 2) {
        #pragma unroll
        for (int q = 0; q < 4; ++q) pbq[q] = b_fc[w * 16 + ks * 4 + q];
    }

    const float* xbase = x + (size_t)(cg * 16 + lcol) * (TSEQ * ISZ) + ks * 8;
    float* outp = out + (size_t)(cg * 16 + lcol) * (FUT * OSZ);

    float cst = 0.f;
    __syncthreads();

#define STAGE_WR(H)                                                            \
    { u32x4 v0 = sreg[(H) * 2], v1 = sreg[(H) * 2 + 1];                        \
      u32x4 hw_, lw_;                                                          \
      hw_[0] = (v0[0] >> 16) | (v0[1] & 0xFFFF0000u);                          \
      hw_[1] = (v0[2] >> 16) | (v0[3] & 0xFFFF0000u);                          \
      hw_[2] = (v1[0] >> 16) | (v1[1] & 0xFFFF0000u);                          \
      hw_[3] = (v1[2] >> 16) | (v1[3] & 0xFFFF0000u);                          \
      lw_[0] = (v0[0] & 0xFFFFu) | (v0[1] << 16);                              \
      lw_[1] = (v0[2] & 0xFFFFu) | (v0[3] << 16);                              \
      lw_[2] = (v1[0] & 0xFFFFu) | (v1[1] << 16);                              \
      lw_[3] = (v1[2] & 0xFFFFu) | (v1[3] << 16);                              \
      const int go = (skb ^ scol) << 3;                                        \
      *(u32x4*)&bHi[H][scol][go] = hw_;                                        \
      *(u32x4*)&bLo[H][scol][go] = lw_; }

#define CONS_KT(H, KTL)                                                        \
    { const int g = ((((KTL) * 4) + ks) ^ lcol) << 3;                          \
      s16x8 bh = *(const s16x8*)&bHi[H][lcol][g];                              \
      s16x8 bl = *(const s16x8*)&bLo[H][lcol][g];                              \
      gA = MFMA_BF16(wH[(H) * 8 + (KTL)], bh, gA, 0, 0, 0);                    \
      gB = MFMA_BF16(wH[(H) * 8 + (KTL)], bl, gB, 0, 0, 0);                    \
      gC = MFMA_BF16(wL[(H) * 8 + (KTL)], bh, gC, 0, 0, 0);                    \
      if (dec && dopred) {                                                     \
          s16x8 fh = *(const s16x8*)(WfcHg + (size_t)prow * HSZ                \
                                     + ((H) * 8 + (KTL)) * 32 + ks * 8);       \
          s16x8 fl = *(const s16x8*)(WfcLg + (size_t)prow * HSZ                \
                                     + ((H) * 8 + (KTL)) * 32 + ks * 8);       \
          pA = MFMA_BF16(fh, bh, pA, 0, 0, 0);                                 \
          pB = MFMA_BF16(fh, bl, pB, 0, 0, 0);                                 \
          pC = MFMA_BF16(fl, bh, pC, 0, 0, 0);                                 \
      } }
#define CONS_HALF(H) \
    CONS_KT(H,0) CONS_KT(H,1) CONS_KT(H,2) CONS_KT(H,3) \
    CONS_KT(H,4) CONS_KT(H,5) CONS_KT(H,6) CONS_KT(H,7)

    #pragma unroll 1
    for (int tt = 0; tt < TSEQ + FUT; ++tt) {
        const bool dec = (tt >= TSEQ);
        // rotating buffers: read buf[(tt+3)&3] (= (tt-1)&3), write buf[tt&3]
        const uint32* sb = hBase + (size_t)((tt + 3) & 3) * 131072 + sboff;
        uint32* hwp      = hBase + (size_t)(tt & 3)       * 131072 + hoff;
        // epoch parity: writer bit for step t = ~(t>>2)&1; reader expects the
        // bit of step tt-1 (tt==0 reads the memset buffer -> expect 0)
        const uint32 wbit = (~((uint32)tt >> 2)) & 1u;
        const uint32 exp  = (tt == 0) ? 0u : ((~(((uint32)tt - 1u) >> 2)) & 1u);

        if (tt == TSEQ) {   // one-time switch to primed (fused) decoder weights
            #pragma unroll
            for (int kt = 0; kt < 16; ++kt) {
                wH[kt] = *(const s16x8*)(WhpHg + (size_t)grow * HSZ + kt * 32 + ks * 8);
                wL[kt] = *(const s16x8*)(WhpLg + (size_t)grow * HSZ + kt * 32 + ks * 8);
            }
        }

        f32x4 gA = {0,0,0,0}, gB = {0,0,0,0}, gC = {0,0,0,0};
        f32x4 pA = {0,0,0,0}, pB = {0,0,0,0}, pC = {0,0,0,0};
        f32x4 xv0 = {0,0,0,0}, xv1 = {0,0,0,0};
        u32x4 sreg[4];

        if (!dec) {   // x loads first; survive across the verify loop in regs
            const float* xp = xbase + (size_t)tt * ISZ;
            xv0 = ldX<0>(xp); xv1 = ldX<16>(xp);
        }

        // ---- speculative load + per-word parity verify (block-wide vote) ----
        int guard = 0;
        for (;;) {
            sreg[0] = ldH_cc<0>(sb);    sreg[1] = ldH_cc<16>(sb);
            sreg[2] = ldH_cc<1024>(sb); sreg[3] = ldH_cc<1040>(sb);
            WAITV(0);
            uint32 bad = 0;
            #pragma unroll
            for (int j = 0; j < 4; ++j) {
                bad |= (sreg[j][0] ^ exp) | (sreg[j][1] ^ exp)
                     | (sreg[j][2] ^ exp) | (sreg[j][3] ^ exp);
            }
            const bool ok = ((bad & 1u) == 0u);
            if (tid == 0) vfail = 0;
            __syncthreads();
            if (!ok) vfail = 1;          // benign multi-writer race (same value)
            __syncthreads();
            if (vfail == 0) break;
            if (++guard > 1024) break;   // wedge -> fast absmax fail, no hang
            __builtin_amdgcn_s_sleep(1);
        }

        if (!dec) {   // x contribution (k-tile 0 of the encoder input)
            s16x8 xh, xl;
            float xv[8];
            *(f32x4*)&xv[0] = xv0; *(f32x4*)&xv[4] = xv1;
            split8(xv, xh, xl);
            gA = MFMA_BF16(ihH, xh, gA, 0, 0, 0);
            gB = MFMA_BF16(ihH, xl, gB, 0, 0, 0);
            gC = MFMA_BF16(ihL, xh, gC, 0, 0, 0);
        }

        // ---- stage both halves to LDS, then consume (weights in AGPRs) ----
        STAGE_WR(0);
        STAGE_WR(1);
        __syncthreads();
        CONS_HALF(0);
        CONS_HALF(1);

        if (dec && dopred) {   // rg0 blocks compute pred for the output
            f32x4 pr = pA + pB + pC;
            const int step = tt - TSEQ;
            #pragma unroll
            for (int q = 0; q < 4; ++q)
                outp[(size_t)step * OSZ + w * 16 + ks * 4 + q] = pr[q] + pbq[q];
        }

        // ---- gates -> LDS bounce ----
        f32x4 gt = gA + gB + gC;
        #pragma unroll
        for (int q = 0; q < 4; ++q)
            gatebuf[w * 16 + ks * 4 + q][lcol] = gt[q];
        __syncthreads();

        // ---- cell update + publish parity-stamped h (fire-and-forget) ----
        {
            float gi = gatebuf[      skb][scol] + (dec ? biP : biv);
            float gf = gatebuf[ 32 + skb][scol] + (dec ? bfP : bfv);
            float gg = gatebuf[ 64 + skb][scol] + (dec ? bgP : bgv);
            float go = gatebuf[ 96 + skb][scol] + (dec ? boP : bov);
            cst = sigm(gf) * cst + sigm(gi) * tanhf(gg);
            float hv = sigm(go) * tanhf(cst);
            uint32 u = __float_as_uint(hv), hu = u & 0xFFFF0000u;
            float rs = hv - __uint_as_float(hu);
            uint32 pk = hu | (__float_as_uint(rs) >> 16);
            pk = (pk & ~1u) | wbit;      // steal lo-LSB for the epoch bit
            st32_cc(hwp, pk);            // NO drain, NO flag, NO barrier
        }
        __syncthreads();   // protect LDS gatebuf/staging reuse next iteration
    }
#undef STAGE_WR
#undef CONS_KT
#undef CONS_HALF
}

extern "C" void kernel_launch(void* const* d_in, const int* in_sizes, int n_in,
                              void* d_out, int out_size, void* d_ws, size_t ws_size,
                              hipStream_t stream)
{
    (void)in_sizes; (void)n_in; (void)out_size; (void)ws_size;
    const float* x    = (const float*)d_in[0];
    const float* W_ih = (const float*)d_in[1];
    const float* W_hh = (const float*)d_in[2];
    const float* b_ih = (const float*)d_in[3];
    const float* b_hh = (const float*)d_in[4];
    const float* W_fc = (const float*)d_in[5];
    const float* b_fc = (const float*)d_in[6];
    float* out = (float*)d_out;

    char* ws = (char*)d_ws;
    uint32* hBase = (uint32*)(ws);                 // 4 x 512 KB rotating h bufs
    u16* WhpH  = (u16*)(ws + (2048u  << 10));      // 2 MB primed Whh' hi
    u16* WhpL  = (u16*)(ws + (4096u  << 10));      // 2 MB primed Whh' lo
    u16* WfcH  = (u16*)(ws + (6144u  << 10));      // 32 KB
    u16* WfcL  = (u16*)(ws + (6176u  << 10));      // 32 KB
    float* bsum  = (float*)(ws + (6208u << 10));   // 8 KB
    float* bsumP = (float*)(ws + (6216u << 10));   // 8 KB

    // zero ONLY buf[3] (read at tt=0; parity 0 == expected for initial state)
    hipMemsetAsync(ws + 3u * (512u << 10), 0, 512u << 10, stream);

    prep_weights<<<2048, 512, 0, stream>>>(W_hh, W_ih, W_fc, b_ih, b_hh, b_fc,
                                           WhpH, WhpL, WfcH, WfcL, bsum, bsumP);

    lstm_mfma6<<<256, 512, 0, stream>>>(x, W_hh, W_ih, b_fc, out,
                                        WhpH, WhpL, WfcH, WfcL, bsum, bsumP,
                                        hBase);
}